// Round 9
// baseline (105.420 us; speedup 1.0000x reference)
//
#include <hip/hip_runtime.h>
#include <hip/hip_bf16.h>

#define EPSBN 1e-5f
#define NEG_SLOPE 0.2f

using f32x4  = __attribute__((ext_vector_type(4))) float;
using bf16x8 = __attribute__((ext_vector_type(8))) short;

// ---- workspace layout (float offsets) ----
#define O_Y1B     0            // 14,258,176 ushorts = 7,129,088 f (dead after pac2)
#define O_G1      7129088      // 445,568 f32
#define O_Y2B     7574656      // 6,889,472 ushorts = 3,444,736 f
#define O_G2      11019392     // 107,648
#define O_WKB2    11127040     // 18,432 ushorts = 9,216 f
#define O_WKB3    11136256     // 73,728 ushorts = 36,864 f
#define O_WKB4    11173120     // 294,912 ushorts = 147,456 f
#define O_WADVR   11320576     // 9,216 f32
#define O_ACC     11329792     // 7,168: acc2[8][64][2] acc3[8][128][2] acc4[8][256][2]
#define O_G3      11336960     // 25,088
#define O_Y3B     11362048     // 3,211,264 ushorts = 1,605,632 f
#define O_Y4B     12967680     // 1,179,648 ushorts = 589,824 f
// total 13,557,504 floats = 54.2 MB
#define A_ACC2    0
#define A_ACC3    1024
#define A_ACC4    3072

__device__ __forceinline__ unsigned short f2bf(float f) {
  union { __hip_bfloat16 b; unsigned short u; } cv;
  cv.b = __float2bfloat16(f);                  // native cast -> v_cvt (RNE)
  return cv.u;
}
__device__ __forceinline__ float bf2f(unsigned short u) {
  union { unsigned int i; float f; } x; x.i = (unsigned int)u << 16; return x.f;
}

// K1: conv1 + avgpool1 + weight repack + zero stat accumulators
#define CONV1_B 7552
#define AVG1_B  1741
#define RPK_B   1548
#define ZERO_B  7
__global__ __launch_bounds__(256) void prep_kernel(
    const float* __restrict__ x, const float* __restrict__ gd,
    const float* __restrict__ w1, const float* __restrict__ b1,
    const float* __restrict__ w2, const float* __restrict__ w3,
    const float* __restrict__ w4, const float* __restrict__ wadv,
    float* __restrict__ ws) {
  const int bi = blockIdx.x, tid = threadIdx.x;
  __shared__ float xs[360];
  __shared__ float wsm[320];
  __shared__ unsigned short ysm[1888];
  if (bi < CONV1_B) {                       // ---- conv1 + lrelu -> y1 bf16 NHWC
    const int n = bi / 59, oh = bi % 59;
    for (int i = tid; i < 320; i += 256)
      wsm[i] = (i < 288) ? w1[(i & 31) * 9 + (i >> 5)] : b1[i - 288];
    const float* src = x + ((size_t)n * 120 + oh * 2) * 120;
    for (int i = tid; i < 360; i += 256) xs[i] = src[i];
    __syncthreads();
    const int co = tid & 31;
    const int ow0 = (tid >> 5) * 8;
    float w[9];
#pragma unroll
    for (int k = 0; k < 9; ++k) w[k] = wsm[k * 32 + co];
    const float bias = wsm[288 + co];
#pragma unroll
    for (int j = 0; j < 8; ++j) {
      int ow = ow0 + j;
      if (ow < 59) {
        float acc = bias;
#pragma unroll
        for (int kh = 0; kh < 3; ++kh)
#pragma unroll
          for (int kw = 0; kw < 3; ++kw)
            acc += xs[kh * 120 + ow * 2 + kw] * w[kh * 3 + kw];
        acc = acc >= 0.0f ? acc : NEG_SLOPE * acc;
        ysm[ow * 32 + co] = f2bf(acc);
      }
    }
    __syncthreads();                        // coalesced row flush
    unsigned int* dst = (unsigned int*)((unsigned short*)(ws + O_Y1B) +
                                        (size_t)(n * 59 + oh) * 1888);
    const unsigned int* s2 = (const unsigned int*)ysm;
    for (int i = tid; i < 944; i += 256) dst[i] = s2[i];
  } else if (bi < CONV1_B + AVG1_B) {       // ---- avgpool gd (120) -> g1 (59)
    int idx = (bi - CONV1_B) * 256 + tid;
    if (idx < 445568) {
      int ow = idx % 59; int t = idx / 59; int oh = t % 59; int n = t / 59;
      const float* gb = gd + (n * 120 + oh * 2) * 120 + ow * 2;
      float s = 0.0f;
#pragma unroll
      for (int kh = 0; kh < 3; ++kh)
#pragma unroll
        for (int kw = 0; kw < 3; ++kw) s += gb[kh * 120 + kw];
      ws[O_G1 + idx] = s * (1.0f / 9.0f);
    }
  } else if (bi < CONV1_B + AVG1_B + RPK_B) {  // ---- weight repack bf16 [s][co][k]
    int idx = (bi - CONV1_B - AVG1_B) * 256 + tid;
    if (idx < 18432) {
      int kk = idx & 31; int t = idx >> 5; int co = t & 63; int tap = t >> 6;
      ((unsigned short*)(ws + O_WKB2))[idx] = f2bf(w2[(co * 32 + kk) * 9 + tap]);
    } else if (idx < 92160) {
      int i = idx - 18432;
      int kk = i & 31; int t = i >> 5; int co = t & 127; int t3 = t >> 7;
      int kc = t3 & 1; int tap = t3 >> 1;
      ((unsigned short*)(ws + O_WKB3))[i] = f2bf(w3[(co * 64 + kc * 32 + kk) * 9 + tap]);
    } else if (idx < 387072) {
      int i = idx - 92160;
      int kk = i & 31; int t = i >> 5; int co = t & 255; int t3 = t >> 8;
      int kc = t3 & 3; int tap = t3 >> 2;
      ((unsigned short*)(ws + O_WKB4))[i] = f2bf(w4[(co * 128 + kc * 32 + kk) * 9 + tap]);
    } else if (idx < 396288) {
      int i = idx - 387072;
      int c = i & 255; int hw = i >> 8;
      ws[O_WADVR + i] = wadv[c * 36 + hw] * (1.0f / 96.0f);
    }
  } else {                                  // ---- zero accumulators
    int idx = (bi - CONV1_B - AVG1_B - RPK_B) * 256 + tid;
    if (idx * 4 < 7168) {
      float4 z = {0.0f, 0.0f, 0.0f, 0.0f};
      *reinterpret_cast<float4*>(ws + O_ACC + idx * 4) = z;
    }
  }
}

// Barrier-free MFMA PacConv, fused: input-BN (from atomic accumulators),
// bias+lrelu, bf16 y via LDS-staged coalesced writes, atomic BN-stat partials.
// POOL: trailing blocks run an independent 3x3/2 avgpool.
template <int CI, int CO, int HI, int HO, int NWM, int NWN, bool BN_IN,
          int NBLK, int MINW, bool POOL>
__global__ __launch_bounds__(256, MINW)
void pac_kernel(const unsigned short* __restrict__ xb, const float* __restrict__ g,
                const float* __restrict__ wkb_f, const float* __restrict__ b,
                const float* __restrict__ gamma, const float* __restrict__ beta,
                const float* __restrict__ accin, float invM,
                unsigned short* __restrict__ yb, float* __restrict__ accout,
                const float* __restrict__ pin, float* __restrict__ pgout,
                int PHI, int PHO, int PTOT) {
  constexpr int KC   = CI / 32;
  constexpr int S    = 9 * KC;
  constexpr int MBLK = NWM * 32;
  constexpr int BSZ  = BN_IN ? CI : 1;
  const unsigned short* wkb = (const unsigned short*)wkb_f;

  const int tid = threadIdx.x;
  const int bi  = blockIdx.x;

  if constexpr (POOL) {
    if (bi >= NBLK) {                        // ---- fused avgpool
      int idx = (bi - NBLK) * 256 + tid;
      if (idx < PTOT) {
        int ow = idx % PHO; int t = idx / PHO; int oh = t % PHO; int n = t / PHO;
        const float* gb = pin + (n * PHI + oh * 2) * PHI + ow * 2;
        float s = 0.0f;
#pragma unroll
        for (int kh = 0; kh < 3; ++kh)
#pragma unroll
          for (int kw = 0; kw < 3; ++kw) s += gb[kh * PHI + kw];
        pgout[idx] = s * (1.0f / 9.0f);
      }
      return;
    }
  }

  __shared__ float bscl[BSZ], bshl[BSZ];
  __shared__ float ps[NWM][CO * 2];
  __shared__ unsigned short ytile[4][2048];  // per-wave 32x64 bf16 C tile

  const int lane = tid & 63;
  const int wv   = tid >> 6;
  const int wm   = wv / NWN, wn = wv % NWN;
  const int blk  = bi;
  const int l15  = lane & 15;
  const int g8   = (lane >> 4) * 8;

  if constexpr (BN_IN) {                     // stats from 8-slot accumulators
    if (tid < CI) {
      float s = 0.0f, q = 0.0f;
#pragma unroll
      for (int sl = 0; sl < 8; ++sl) {
        s += accin[(sl * CI + tid) * 2 + 0];
        q += accin[(sl * CI + tid) * 2 + 1];
      }
      float m = s * invM;
      float var = q * invM - m * m;
      float sc = gamma[tid] * rsqrtf(var + EPSBN);
      bscl[tid] = sc;
      bshl[tid] = beta[tid] - m * sc;
    }
    __syncthreads();
  }

  float kk[2][9];
  int   xo[2];
#pragma unroll
  for (int mt = 0; mt < 2; ++mt) {
    int p  = blk * MBLK + wm * 32 + mt * 16 + l15;
    int ow = p % HO, oh = (p / HO) % HO, n = p / (HO * HO);
    const float* gn = g + n * (HI * HI);
    float gc = gn[(oh * 2 + 1) * HI + ow * 2 + 1];
#pragma unroll
    for (int t = 0; t < 9; ++t) {
      float d = gn[(oh * 2 + t / 3) * HI + ow * 2 + (t % 3)] - gc;
      kk[mt][t] = __expf(-0.5f * d * d);
    }
    xo[mt] = ((n * HI + oh * 2) * HI + ow * 2) * CI;
  }

  f32x4 acc[2][4];
#pragma unroll
  for (int nt = 0; nt < 4; ++nt) {
    float bv = b[wn * 64 + nt * 16 + l15];
#pragma unroll
    for (int mt = 0; mt < 2; ++mt) acc[mt][nt] = (f32x4){bv, bv, bv, bv};
  }

#pragma unroll
  for (int i = 0; i < S; ++i) {
    const int t  = i / KC;                   // compile-time
    const int kc = i % KC;                   // compile-time
    const int xoff = ((t / 3) * HI + (t % 3)) * CI + kc * 32 + g8;
    bf16x8 bfv[4];
#pragma unroll
    for (int nt = 0; nt < 4; ++nt)
      bfv[nt] = *(const bf16x8*)(wkb + ((size_t)i * CO + wn * 64 + nt * 16 + l15) * 32 + g8);
    bf16x8 af[2];
#pragma unroll
    for (int mt = 0; mt < 2; ++mt) {
      bf16x8 u = *(const bf16x8*)(xb + xo[mt] + xoff);
      float v[8];
#pragma unroll
      for (int j = 0; j < 8; ++j) v[j] = bf2f((unsigned short)u[j]);
      if constexpr (BN_IN) {
        const int c0 = kc * 32 + g8;
#pragma unroll
        for (int j = 0; j < 8; ++j) v[j] = v[j] * bscl[c0 + j] + bshl[c0 + j];
      }
      const float kv = kk[mt][t];
#pragma unroll
      for (int j = 0; j < 8; ++j) v[j] *= kv;
#pragma unroll
      for (int j = 0; j < 8; ++j) af[mt][j] = (short)f2bf(v[j]);
    }
#pragma unroll
    for (int mt = 0; mt < 2; ++mt)
#pragma unroll
      for (int nt = 0; nt < 4; ++nt)
        acc[mt][nt] = __builtin_amdgcn_mfma_f32_16x16x32_bf16(af[mt], bfv[nt], acc[mt][nt], 0, 0, 0);
  }

  // epilogue: lrelu -> ytile (LDS) + per-channel (sum, sumsq) partials
#pragma unroll
  for (int nt = 0; nt < 4; ++nt) {
    const int co = wn * 64 + nt * 16 + l15;
    float s = 0.0f, q = 0.0f;
#pragma unroll
    for (int mt = 0; mt < 2; ++mt)
#pragma unroll
      for (int r = 0; r < 4; ++r) {
        float v = acc[mt][nt][r];
        v = v >= 0.0f ? v : NEG_SLOPE * v;
        int row = mt * 16 + ((lane >> 4) << 2) + r;
        ytile[wv][row * 64 + nt * 16 + l15] = f2bf(v);
        s += v; q += v * v;
      }
    s += __shfl_xor(s, 16, 64); q += __shfl_xor(q, 16, 64);
    s += __shfl_xor(s, 32, 64); q += __shfl_xor(q, 32, 64);
    if (l15 == lane) { ps[wm][co * 2 + 0] = s; ps[wm][co * 2 + 1] = q; }
  }
  __syncthreads();                           // ytile + ps visible
  // coalesced tile flush: 32 rows x 128B per wave
  {
    unsigned short* dbase = yb + (size_t)(blk * MBLK + wm * 32) * CO + wn * 64;
    const uint4* srcT = (const uint4*)ytile[wv];
#pragma unroll
    for (int i = 0; i < 4; ++i) {
      int row = i * 8 + (lane >> 3);
      int u4  = lane & 7;
      *(uint4*)(dbase + (size_t)row * CO + u4 * 8) = srcT[row * 8 + u4];
    }
  }
  if (tid < CO) {
    float s = 0.0f, q = 0.0f;
#pragma unroll
    for (int wmx = 0; wmx < NWM; ++wmx) { s += ps[wmx][tid * 2]; q += ps[wmx][tid * 2 + 1]; }
    atomicAdd(&accout[((blk & 7) * CO + tid) * 2 + 0], s);
    atomicAdd(&accout[((blk & 7) * CO + tid) * 2 + 1], q);
  }
}

// EqualLinear; BN4 scale/shift from accumulators; y4 bf16
__global__ void linear_kernel(const unsigned short* __restrict__ y4b,
                              const float* __restrict__ acc4,
                              const float* __restrict__ bg4, const float* __restrict__ bb4,
                              const float* __restrict__ wadvr, const float* __restrict__ badv,
                              float* __restrict__ out) {
  int n = blockIdx.x, t = threadIdx.x;
  float s0 = 0.0f, q0 = 0.0f;
#pragma unroll
  for (int sl = 0; sl < 8; ++sl) {
    s0 += acc4[(sl * 256 + t) * 2 + 0];
    q0 += acc4[(sl * 256 + t) * 2 + 1];
  }
  float m = s0 * (1.0f / 4608.0f);
  float var = q0 * (1.0f / 4608.0f) - m * m;
  float sc = bg4[t] * rsqrtf(var + EPSBN);
  float sh = bb4[t] - m * sc;
  float s = 0.0f;
  for (int j = t; j < 9216; j += 256)
    s += (bf2f(y4b[n * 9216 + j]) * sc + sh) * wadvr[j];
  __shared__ float ss[256];
  ss[t] = s; __syncthreads();
  for (int off = 128; off > 0; off >>= 1) {
    if (t < off) ss[t] += ss[t + off];
    __syncthreads();
  }
  if (t == 0) out[n] = ss[0] + badv[0];
}

extern "C" void kernel_launch(void* const* d_in, const int* in_sizes, int n_in,
                              void* d_out, int out_size, void* d_ws, size_t ws_size,
                              hipStream_t stream) {
  const float* x    = (const float*)d_in[0];
  const float* gd   = (const float*)d_in[1];
  const float* w1   = (const float*)d_in[2];
  const float* b1   = (const float*)d_in[3];
  const float* w2   = (const float*)d_in[4];
  const float* b2   = (const float*)d_in[5];
  const float* w3   = (const float*)d_in[6];
  const float* b3   = (const float*)d_in[7];
  const float* w4   = (const float*)d_in[8];
  const float* b4   = (const float*)d_in[9];
  const float* bg2  = (const float*)d_in[10];
  const float* bb2  = (const float*)d_in[11];
  const float* bg3  = (const float*)d_in[12];
  const float* bb3  = (const float*)d_in[13];
  const float* bg4  = (const float*)d_in[14];
  const float* bb4  = (const float*)d_in[15];
  const float* wadv = (const float*)d_in[16];
  const float* badv = (const float*)d_in[17];
  float* out = (float*)d_out;
  float* ws  = (float*)d_ws;

  unsigned short* y1b = (unsigned short*)(ws + O_Y1B);
  unsigned short* y2b = (unsigned short*)(ws + O_Y2B);
  unsigned short* y3b = (unsigned short*)(ws + O_Y3B);
  unsigned short* y4b = (unsigned short*)(ws + O_Y4B);
  float* acc2 = ws + O_ACC + A_ACC2;
  float* acc3 = ws + O_ACC + A_ACC3;
  float* acc4 = ws + O_ACC + A_ACC4;

  // K1: conv1 + avgpool1 + repack + zero accumulators
  prep_kernel<<<CONV1_B + AVG1_B + RPK_B + ZERO_B, 256, 0, stream>>>(
      x, gd, w1, b1, w2, w3, w4, wadv, ws);

  // K2: pac2 (841 blocks) + avgpool g1->g2 (421 blocks)
  pac_kernel<32, 64, 59, 29, 4, 1, false, 841, 3, true>
      <<<1262, 256, 0, stream>>>(y1b, ws + O_G1, ws + O_WKB2, b2,
                                 nullptr, nullptr, nullptr, 0.0f,
                                 y2b, acc2,
                                 ws + O_G1, ws + O_G2, 59, 29, 107648);

  // K3: pac3 (392 blocks, BN2 from acc2) + avgpool g2->g3 (98 blocks)
  pac_kernel<64, 128, 29, 14, 2, 2, true, 392, 2, true>
      <<<490, 256, 0, stream>>>(y2b, ws + O_G2, ws + O_WKB3, b3,
                                bg2, bb2, acc2, 1.0f / 107648.0f,
                                y3b, acc3,
                                ws + O_G2, ws + O_G3, 29, 14, 25088);

  // K4: pac4 fused single-pass (144 blocks, BN3 from acc3) -> y4 bf16 + stats
  pac_kernel<128, 256, 14, 6, 1, 4, true, 144, 2, false>
      <<<144, 256, 0, stream>>>(y3b, ws + O_G3, ws + O_WKB4, b4,
                                bg3, bb3, acc3, 1.0f / 25088.0f,
                                y4b, acc4,
                                nullptr, nullptr, 0, 0, 0);

  // K5: EqualLinear with in-prologue BN4 stats
  linear_kernel<<<128, 256, 0, stream>>>(y4b, acc4, bg4, bb4,
                                         ws + O_WADVR, badv, out);
}